// Round 1
// baseline (352.042 us; speedup 1.0000x reference)
//
#include <hip/hip_runtime.h>

// BinaryLinear: out[32768,1024] = x[32768,1024] @ (sign(W)*scale)^T + b
// Strategy: GEMM in bf16 MFMA with EXACT ±1 bf16 weights; scale applied in
// fp32 epilogue => only x suffers bf16 rounding (error ~1e-3 << 0.096 thr).

typedef short short8 __attribute__((ext_vector_type(8)));
typedef float f32x4 __attribute__((ext_vector_type(4)));

#define BATCH 32768
#define IN_F  1024
#define OUT_F 1024
#define EPS   1e-6f

#define BM 128
#define BN 128
#define BK 32

__device__ __forceinline__ ushort f2bf(float f) {
  unsigned u = __builtin_bit_cast(unsigned, f);
  u += 0x7FFFu + ((u >> 16) & 1u);   // round-to-nearest-even
  return (ushort)(u >> 16);
}

// ---- Kernel 1: per-row scale + binarized bf16 weights ----
// 1024 blocks x 64 threads (1 wave per output row).
__global__ void bin_kernel(const float* __restrict__ W,
                           ushort* __restrict__ Wb,
                           float* __restrict__ scale) {
  int row = blockIdx.x;
  int t = threadIdx.x;
  const float4* wr = (const float4*)(W + (size_t)row * IN_F);
  ushort4* wb = (ushort4*)(Wb + (size_t)row * IN_F);
  float s = 0.f;
#pragma unroll
  for (int i = 0; i < 4; ++i) {
    float4 v = wr[i * 64 + t];
    ushort4 u;
    u.x = (v.x >= 0.f) ? 0x3F80 : 0xBF80;   // ±1.0 in bf16 (exact)
    u.y = (v.y >= 0.f) ? 0x3F80 : 0xBF80;
    u.z = (v.z >= 0.f) ? 0x3F80 : 0xBF80;
    u.w = (v.w >= 0.f) ? 0x3F80 : 0xBF80;
    wb[i * 64 + t] = u;
    s += fabsf(v.x) + fabsf(v.y) + fabsf(v.z) + fabsf(v.w);
  }
#pragma unroll
  for (int o = 32; o > 0; o >>= 1) s += __shfl_down(s, o);
  if (t == 0) scale[row] = fmaxf(s * (1.0f / (float)IN_F), EPS);
}

// ---- Kernel 2: 128x128 tile MFMA GEMM (m97 structure, reg-staged A/B) ----
// A = x (f32 -> bf16 on the fly), B = Wb (bf16 ±1, row-major [N][K] = B^T).
// LDS tiles [128][32] bf16, XOR-swizzled (row&7)<<3 ushorts on BOTH the
// ds_write and ds_read sides -> conflict-free ds_read_b128 fragments.
__global__ void gemm_kernel(const float* __restrict__ X,
                            const ushort* __restrict__ Wb,
                            const float* __restrict__ scale,
                            const float* __restrict__ bias,
                            float* __restrict__ out) {
  __shared__ __align__(16) ushort lA[BM * BK];   // 8 KB
  __shared__ __align__(16) ushort lB[BN * BK];   // 8 KB

  // XCD swizzle: each XCD gets contiguous M-panels (x-panel L2 reuse).
  int bid = blockIdx.x;                 // 2048 blocks, %8==0 -> bijective
  int g = (bid & 7) * 256 + (bid >> 3);
  int mt = g >> 3;                      // 0..255
  int nt = g & 7;                       // 0..7
  int rowBase = mt * BM;
  int colBase = nt * BN;

  int t = threadIdx.x;                  // 256 threads = 4 waves (2x2)
  int lane = t & 63;
  int wave = t >> 6;
  int wr = wave >> 1;                   // wave row 0..1 (64 rows each)
  int wc = wave & 1;                    // wave col 0..1 (64 cols each)

  f32x4 acc[4][4];
#pragma unroll
  for (int m = 0; m < 4; ++m)
#pragma unroll
    for (int n = 0; n < 4; ++n) acc[m][n] = (f32x4){0.f, 0.f, 0.f, 0.f};

  for (int kk = 0; kk < IN_F / BK; ++kk) {
    int k0 = kk * BK;
    __syncthreads();   // previous compute done before overwriting LDS

    // stage A: 128x32 f32 -> bf16.  idx 0..511: row=idx>>2, 16B-group=idx&3
#pragma unroll
    for (int i = 0; i < 2; ++i) {
      int idx = t + 256 * i;
      int r = idx >> 2, c16 = idx & 3;
      const float4* gp =
          (const float4*)(X + (size_t)(rowBase + r) * IN_F + k0 + c16 * 8);
      float4 v0 = gp[0];
      float4 v1 = gp[1];
      short8 u;
      u[0] = (short)f2bf(v0.x); u[1] = (short)f2bf(v0.y);
      u[2] = (short)f2bf(v0.z); u[3] = (short)f2bf(v0.w);
      u[4] = (short)f2bf(v1.x); u[5] = (short)f2bf(v1.y);
      u[6] = (short)f2bf(v1.z); u[7] = (short)f2bf(v1.w);
      int off = (r * BK + c16 * 8) ^ ((r & 7) << 3);
      *(short8*)(&lA[off]) = u;
    }
    // stage B: 128x32 bf16 straight copy
#pragma unroll
    for (int i = 0; i < 2; ++i) {
      int idx = t + 256 * i;
      int r = idx >> 2, c16 = idx & 3;
      const short8* gp =
          (const short8*)(Wb + (size_t)(colBase + r) * IN_F + k0 + c16 * 8);
      short8 u = *gp;
      int off = (r * BK + c16 * 8) ^ ((r & 7) << 3);
      *(short8*)(&lB[off]) = u;
    }
    __syncthreads();

    // fragments: lane l -> row (l&15) of 16-row frag, k = (l>>4)*8 .. +7
    short8 af[4], bfr[4];
#pragma unroll
    for (int m = 0; m < 4; ++m) {
      int r = wr * 64 + m * 16 + (lane & 15);
      int off = (r * BK + (lane >> 4) * 8) ^ ((r & 7) << 3);
      af[m] = *(const short8*)(&lA[off]);
    }
#pragma unroll
    for (int n = 0; n < 4; ++n) {
      int r = wc * 64 + n * 16 + (lane & 15);
      int off = (r * BK + (lane >> 4) * 8) ^ ((r & 7) << 3);
      bfr[n] = *(const short8*)(&lB[off]);
    }
#pragma unroll
    for (int m = 0; m < 4; ++m)
#pragma unroll
      for (int n = 0; n < 4; ++n)
        acc[m][n] = __builtin_amdgcn_mfma_f32_16x16x32_bf16(
            af[m], bfr[n], acc[m][n], 0, 0, 0);
  }

  // epilogue: C/D layout col=lane&15, row=(lane>>4)*4+j  (m89-verified)
#pragma unroll
  for (int n = 0; n < 4; ++n) {
    int col = colBase + wc * 64 + n * 16 + (lane & 15);
    float sc = scale[col];
    float bs = bias[col];
#pragma unroll
    for (int m = 0; m < 4; ++m) {
      int r0 = rowBase + wr * 64 + m * 16 + ((lane >> 4) << 2);
#pragma unroll
      for (int j = 0; j < 4; ++j) {
        out[(size_t)(r0 + j) * OUT_F + col] = acc[m][n][j] * sc + bs;
      }
    }
  }
}

extern "C" void kernel_launch(void* const* d_in, const int* in_sizes, int n_in,
                              void* d_out, int out_size, void* d_ws,
                              size_t ws_size, hipStream_t stream) {
  const float* x = (const float*)d_in[0];
  const float* W = (const float*)d_in[1];
  const float* b = (const float*)d_in[2];
  float* out = (float*)d_out;

  float* scale = (float*)d_ws;                       // 4 KB
  ushort* Wb = (ushort*)((char*)d_ws + 4096);        // 2 MB bf16 weights

  bin_kernel<<<OUT_F, 64, 0, stream>>>(W, Wb, scale);

  dim3 grid((BATCH / BM) * (OUT_F / BN));            // 256*8 = 2048
  gemm_kernel<<<grid, 256, 0, stream>>>(x, Wb, scale, b, out);
}

// Round 3
// 302.568 us; speedup vs baseline: 1.1635x; 1.1635x over previous
//
#include <hip/hip_runtime.h>

// BinaryLinear: out[32768,1024] = x[32768,1024] @ (sign(W)*scale)^T + b
// R3 == R2 resubmit (R2 hit GPUAcquisitionTimeout, never ran):
//   pre-convert x -> bf16 (ws), then m97-structure GEMM:
//   global_load_lds width=16, BK=64, linear LDS, 128x128 tile, 4 waves.
//   Weights are EXACT +-1 bf16; fp32 scale+bias in epilogue.

typedef short short8 __attribute__((ext_vector_type(8)));
typedef float f32x4 __attribute__((ext_vector_type(4)));

#define BATCH 32768
#define IN_F  1024
#define OUT_F 1024
#define EPS   1e-6f

#define BM 128
#define BN 128

__device__ __forceinline__ ushort f2bf(float f) {
  unsigned u = __builtin_bit_cast(unsigned, f);
  u += 0x7FFFu + ((u >> 16) & 1u);   // round-to-nearest-even
  return (ushort)(u >> 16);
}

// async global->LDS, 16B per lane; LDS dest is wave-uniform base + lane*16
__device__ __forceinline__ void gload_lds16(const void* g, void* l) {
  __builtin_amdgcn_global_load_lds(
      (const __attribute__((address_space(1))) unsigned*)g,
      (__attribute__((address_space(3))) unsigned*)l, 16, 0, 0);
}

// ---- Kernel 1: per-row scale + binarized bf16 weights ----
// 256 blocks x 256 threads; one wave per output row (4 rows/block).
__global__ void bin_kernel(const float* __restrict__ W,
                           ushort* __restrict__ Wb,
                           float* __restrict__ scale) {
  int row = blockIdx.x * 4 + (threadIdx.x >> 6);
  int t = threadIdx.x & 63;
  const float4* wr = (const float4*)(W + (size_t)row * IN_F);
  ushort4* wb = (ushort4*)(Wb + (size_t)row * IN_F);
  float s = 0.f;
#pragma unroll
  for (int i = 0; i < 4; ++i) {
    float4 v = wr[i * 64 + t];
    ushort4 u;
    u.x = (v.x >= 0.f) ? 0x3F80 : 0xBF80;   // +-1.0 bf16 (exact)
    u.y = (v.y >= 0.f) ? 0x3F80 : 0xBF80;
    u.z = (v.z >= 0.f) ? 0x3F80 : 0xBF80;
    u.w = (v.w >= 0.f) ? 0x3F80 : 0xBF80;
    wb[i * 64 + t] = u;
    s += fabsf(v.x) + fabsf(v.y) + fabsf(v.z) + fabsf(v.w);
  }
#pragma unroll
  for (int o = 32; o > 0; o >>= 1) s += __shfl_down(s, o);
  if (t == 0) scale[row] = fmaxf(s * (1.0f / (float)IN_F), EPS);
}

// ---- Kernel 2: x f32 -> bf16 (memory-bound, one float4 per thread) ----
__global__ void cvt_kernel(const float* __restrict__ X,
                           ushort* __restrict__ Xb) {
  size_t idx = (size_t)blockIdx.x * 256 + threadIdx.x;   // 8M threads
  float4 v = ((const float4*)X)[idx];
  ushort4 u;
  u.x = f2bf(v.x); u.y = f2bf(v.y); u.z = f2bf(v.z); u.w = f2bf(v.w);
  ((ushort4*)Xb)[idx] = u;
}

// ---- Kernel 3 (fast path): m97-structure bf16 MFMA GEMM ----
// A = Xb [32768][1024] bf16, B = Wb [1024][1024] bf16 (row-major = B^T).
// LDS: linear [128][64] bf16 tiles (16 KB each), staged via global_load_lds.
__global__ void gemm_fast(const ushort* __restrict__ Xb,
                          const ushort* __restrict__ Wb,
                          const float* __restrict__ scale,
                          const float* __restrict__ bias,
                          float* __restrict__ out) {
  __shared__ __align__(16) ushort lA[BM * 64];   // 16 KB
  __shared__ __align__(16) ushort lB[BN * 64];   // 16 KB

  // XCD swizzle (T1): 2048 blocks, each XCD owns 32 contiguous M-panels,
  // nt cycles fastest -> x panel (256 KB) L2-resident across its 8 N-tiles.
  int bid = blockIdx.x;
  int g = (bid & 7) * 256 + (bid >> 3);
  int mt = g >> 3;
  int nt = g & 7;
  int rowBase = mt * BM;
  int colBase = nt * BN;

  int t = threadIdx.x;          // 256 threads = 4 waves (2x2)
  int lane = t & 63;
  int wave = t >> 6;
  int wr = wave >> 1;
  int wc = wave & 1;

  // staging addresses: issue j covers 8 rows (8 lanes/row, 16 B each)
  int srow = (lane >> 3);               // 0..7 within issue
  int scol = (lane & 7) * 8;            // bf16 col within 64
  const ushort* gA = Xb + (size_t)(rowBase + wave * 8 + srow) * IN_F + scol;
  const ushort* gB = Wb + (size_t)(colBase + wave * 8 + srow) * IN_F + scol;
  ushort* lA_base = &lA[(wave * 8) * 64];
  ushort* lB_base = &lB[(wave * 8) * 64];

  f32x4 acc[4][4];
#pragma unroll
  for (int m = 0; m < 4; ++m)
#pragma unroll
    for (int n = 0; n < 4; ++n) acc[m][n] = (f32x4){0.f, 0.f, 0.f, 0.f};

  for (int kk = 0; kk < IN_F / 64; ++kk) {
    int k0 = kk * 64;
    __syncthreads();   // previous compute done before overwriting LDS

#pragma unroll
    for (int j = 0; j < 4; ++j) {      // 4 issues x 32 rows apart
      gload_lds16(gA + k0 + (size_t)j * 32 * IN_F, lA_base + j * 32 * 64);
      gload_lds16(gB + k0 + (size_t)j * 32 * IN_F, lB_base + j * 32 * 64);
    }
    __syncthreads();   // compiler drains vmcnt(0) here (m97 structure)

    short8 af[4][2], bfx[4][2];
#pragma unroll
    for (int m = 0; m < 4; ++m)
#pragma unroll
      for (int ks = 0; ks < 2; ++ks) {
        int row = wr * 64 + m * 16 + (lane & 15);
        af[m][ks] = *(const short8*)(&lA[row * 64 + ks * 32 + (lane >> 4) * 8]);
      }
#pragma unroll
    for (int n = 0; n < 4; ++n)
#pragma unroll
      for (int ks = 0; ks < 2; ++ks) {
        int row = wc * 64 + n * 16 + (lane & 15);
        bfx[n][ks] = *(const short8*)(&lB[row * 64 + ks * 32 + (lane >> 4) * 8]);
      }
#pragma unroll
    for (int ks = 0; ks < 2; ++ks)
#pragma unroll
      for (int m = 0; m < 4; ++m)
#pragma unroll
        for (int n = 0; n < 4; ++n)
          acc[m][n] = __builtin_amdgcn_mfma_f32_16x16x32_bf16(
              af[m][ks], bfx[n][ks], acc[m][n], 0, 0, 0);
  }

  // epilogue: C/D layout col=lane&15, row=(lane>>4)*4+j (m89-verified)
#pragma unroll
  for (int n = 0; n < 4; ++n) {
    int col = colBase + wc * 64 + n * 16 + (lane & 15);
    float sc = scale[col];
    float bs = bias[col];
#pragma unroll
    for (int m = 0; m < 4; ++m) {
      int r0 = rowBase + wr * 64 + m * 16 + ((lane >> 4) << 2);
#pragma unroll
      for (int j = 0; j < 4; ++j) {
        out[(size_t)(r0 + j) * OUT_F + col] = acc[m][n][j] * sc + bs;
      }
    }
  }
}

// ---- Fallback GEMM (R1, reg-staged f32->bf16 on the fly) ----
__global__ void gemm_kernel(const float* __restrict__ X,
                            const ushort* __restrict__ Wb,
                            const float* __restrict__ scale,
                            const float* __restrict__ bias,
                            float* __restrict__ out) {
  __shared__ __align__(16) ushort lA[BM * 32];
  __shared__ __align__(16) ushort lB[BN * 32];

  int bid = blockIdx.x;
  int g = (bid & 7) * 256 + (bid >> 3);
  int mt = g >> 3;
  int nt = g & 7;
  int rowBase = mt * BM;
  int colBase = nt * BN;

  int t = threadIdx.x;
  int lane = t & 63;
  int wave = t >> 6;
  int wr = wave >> 1;
  int wc = wave & 1;

  f32x4 acc[4][4];
#pragma unroll
  for (int m = 0; m < 4; ++m)
#pragma unroll
    for (int n = 0; n < 4; ++n) acc[m][n] = (f32x4){0.f, 0.f, 0.f, 0.f};

  for (int kk = 0; kk < IN_F / 32; ++kk) {
    int k0 = kk * 32;
    __syncthreads();
#pragma unroll
    for (int i = 0; i < 2; ++i) {
      int idx = t + 256 * i;
      int r = idx >> 2, c16 = idx & 3;
      const float4* gp =
          (const float4*)(X + (size_t)(rowBase + r) * IN_F + k0 + c16 * 8);
      float4 v0 = gp[0];
      float4 v1 = gp[1];
      short8 u;
      u[0] = (short)f2bf(v0.x); u[1] = (short)f2bf(v0.y);
      u[2] = (short)f2bf(v0.z); u[3] = (short)f2bf(v0.w);
      u[4] = (short)f2bf(v1.x); u[5] = (short)f2bf(v1.y);
      u[6] = (short)f2bf(v1.z); u[7] = (short)f2bf(v1.w);
      int off = (r * 32 + c16 * 8) ^ ((r & 7) << 3);
      *(short8*)(&lA[off]) = u;
    }
#pragma unroll
    for (int i = 0; i < 2; ++i) {
      int idx = t + 256 * i;
      int r = idx >> 2, c16 = idx & 3;
      const short8* gp =
          (const short8*)(Wb + (size_t)(colBase + r) * IN_F + k0 + c16 * 8);
      short8 u = *gp;
      int off = (r * 32 + c16 * 8) ^ ((r & 7) << 3);
      *(short8*)(&lB[off]) = u;
    }
    __syncthreads();

    short8 af[4], bfr[4];
#pragma unroll
    for (int m = 0; m < 4; ++m) {
      int r = wr * 64 + m * 16 + (lane & 15);
      int off = (r * 32 + (lane >> 4) * 8) ^ ((r & 7) << 3);
      af[m] = *(const short8*)(&lA[off]);
    }
#pragma unroll
    for (int n = 0; n < 4; ++n) {
      int r = wc * 64 + n * 16 + (lane & 15);
      int off = (r * 32 + (lane >> 4) * 8) ^ ((r & 7) << 3);
      bfr[n] = *(const short8*)(&lB[off]);
    }
#pragma unroll
    for (int m = 0; m < 4; ++m)
#pragma unroll
      for (int n = 0; n < 4; ++n)
        acc[m][n] = __builtin_amdgcn_mfma_f32_16x16x32_bf16(
            af[m], bfr[n], acc[m][n], 0, 0, 0);
  }

#pragma unroll
  for (int n = 0; n < 4; ++n) {
    int col = colBase + wc * 64 + n * 16 + (lane & 15);
    float sc = scale[col];
    float bs = bias[col];
#pragma unroll
    for (int m = 0; m < 4; ++m) {
      int r0 = rowBase + wr * 64 + m * 16 + ((lane >> 4) << 2);
#pragma unroll
      for (int j = 0; j < 4; ++j) {
        out[(size_t)(r0 + j) * OUT_F + col] = acc[m][n][j] * sc + bs;
      }
    }
  }
}

extern "C" void kernel_launch(void* const* d_in, const int* in_sizes, int n_in,
                              void* d_out, int out_size, void* d_ws,
                              size_t ws_size, hipStream_t stream) {
  const float* x = (const float*)d_in[0];
  const float* W = (const float*)d_in[1];
  const float* b = (const float*)d_in[2];
  float* out = (float*)d_out;

  float* scale = (float*)d_ws;                               // 4 KB
  ushort* Wb = (ushort*)((char*)d_ws + 4096);                // 2 MB
  ushort* xb = (ushort*)((char*)d_ws + 4096 + 2097152);      // 64 MB
  const size_t need = 4096 + 2097152 + (size_t)BATCH * IN_F * 2;

  bin_kernel<<<OUT_F / 4, 256, 0, stream>>>(W, Wb, scale);

  dim3 grid((BATCH / BM) * (OUT_F / BN));                    // 2048
  if (ws_size >= need) {
    cvt_kernel<<<(BATCH * IN_F / 4) / 256, 256, 0, stream>>>(x, xb);
    gemm_fast<<<grid, 256, 0, stream>>>(xb, Wb, scale, b, out);
  } else {
    gemm_kernel<<<grid, 256, 0, stream>>>(x, Wb, scale, b, out);
  }
}

// Round 10
// 298.266 us; speedup vs baseline: 1.1803x; 1.0144x over previous
//
#include <hip/hip_runtime.h>

// BinaryLinear: out[32768,1024] = x[32768,1024] @ (sign(W)*scale)^T + b
// R10 == R4..R9 resubmit (six broker-infra failures in a row; kernel has
// never executed). 256x256 8-phase GEMM (T1+T2+T3+T4+T5, m201 template):
//   8 waves (2Mx4N), BK=64, 128 KiB dbuf LDS, XOR-swizzle (row&7)<<4,
//   counted vmcnt(6) at phases 4/8, raw s_barrier, setprio around MFMA.
//   x pre-converted to bf16 (cvt_kernel); weights EXACT +-1 bf16; fp32
//   scale+bias epilogue.

typedef short short8 __attribute__((ext_vector_type(8)));
typedef float f32x4 __attribute__((ext_vector_type(4)));

#define BATCH 32768
#define IN_F  1024
#define OUT_F 1024
#define EPS   1e-6f

__device__ __forceinline__ ushort f2bf(float f) {
  unsigned u = __builtin_bit_cast(unsigned, f);
  u += 0x7FFFu + ((u >> 16) & 1u);   // round-to-nearest-even
  return (ushort)(u >> 16);
}

// async global->LDS, 16B/lane; LDS dest = wave-uniform base + lane*16
__device__ __forceinline__ void gload_lds16(const void* g, void* l) {
  __builtin_amdgcn_global_load_lds(
      (const __attribute__((address_space(1))) unsigned*)g,
      (__attribute__((address_space(3))) unsigned*)l, 16, 0, 0);
}

// ---- Kernel 1: per-row scale + binarized bf16 weights ----
__global__ void bin_kernel(const float* __restrict__ W,
                           ushort* __restrict__ Wb,
                           float* __restrict__ scale) {
  int row = blockIdx.x * 4 + (threadIdx.x >> 6);
  int t = threadIdx.x & 63;
  const float4* wr = (const float4*)(W + (size_t)row * IN_F);
  ushort4* wb = (ushort4*)(Wb + (size_t)row * IN_F);
  float s = 0.f;
#pragma unroll
  for (int i = 0; i < 4; ++i) {
    float4 v = wr[i * 64 + t];
    ushort4 u;
    u.x = (v.x >= 0.f) ? 0x3F80 : 0xBF80;
    u.y = (v.y >= 0.f) ? 0x3F80 : 0xBF80;
    u.z = (v.z >= 0.f) ? 0x3F80 : 0xBF80;
    u.w = (v.w >= 0.f) ? 0x3F80 : 0xBF80;
    wb[i * 64 + t] = u;
    s += fabsf(v.x) + fabsf(v.y) + fabsf(v.z) + fabsf(v.w);
  }
#pragma unroll
  for (int o = 32; o > 0; o >>= 1) s += __shfl_down(s, o);
  if (t == 0) scale[row] = fmaxf(s * (1.0f / (float)IN_F), EPS);
}

// ---- Kernel 2: x f32 -> bf16 ----
__global__ void cvt_kernel(const float* __restrict__ X,
                           ushort* __restrict__ Xb) {
  size_t idx = (size_t)blockIdx.x * 256 + threadIdx.x;
  float4 v = ((const float4*)X)[idx];
  ushort4 u;
  u.x = f2bf(v.x); u.y = f2bf(v.y); u.z = f2bf(v.z); u.w = f2bf(v.w);
  ((ushort4*)Xb)[idx] = u;
}

// ---- 8-phase GEMM helpers ----
__device__ __forceinline__ void rd4(short8 (*dst)[2], const char* base,
                                    int c0, int c1) {
#pragma unroll
  for (int m = 0; m < 4; ++m) {
    dst[m][0] = *(const short8*)(base + m * 2048 + c0);
    dst[m][1] = *(const short8*)(base + m * 2048 + c1);
  }
}
__device__ __forceinline__ void rd2(short8 (*dst)[2], const char* base,
                                    int c0, int c1) {
#pragma unroll
  for (int n = 0; n < 2; ++n) {
    dst[n][0] = *(const short8*)(base + n * 2048 + c0);
    dst[n][1] = *(const short8*)(base + n * 2048 + c1);
  }
}
template <int MB, int NB>
__device__ __forceinline__ void mmq(f32x4 (*acc)[4], const short8 (*a)[2],
                                    const short8 (*b)[2]) {
#pragma unroll
  for (int ks = 0; ks < 2; ++ks)
#pragma unroll
    for (int m = 0; m < 4; ++m)
#pragma unroll
      for (int n = 0; n < 2; ++n)
        acc[MB + m][NB + n] = __builtin_amdgcn_mfma_f32_16x16x32_bf16(
            a[m][ks], b[n][ks], acc[MB + m][NB + n], 0, 0, 0);
}

#define FENCE() do { __builtin_amdgcn_sched_barrier(0); \
                     asm volatile("" ::: "memory"); } while (0)
#define BAR()   do { FENCE(); __builtin_amdgcn_s_barrier(); FENCE(); } while (0)
#define MFMA_SEC(stmt) do { BAR(); __builtin_amdgcn_s_setprio(1); stmt; \
                            __builtin_amdgcn_s_setprio(0); BAR(); } while (0)

// ---- Kernel 3: 256x256 8-phase bf16 MFMA GEMM ----
// A = Xb [32768][1024] bf16, B = Wb [1024][1024] bf16 (row-major = B^T).
// LDS: A buf0 [0,32K) A buf1 [32K,64K) B buf0 [64K,96K) B buf1 [96K,128K).
// Tile layout per operand buffer: [256 rows][64 k] bf16, row stride 128 B,
// byte ^= ((row&7)<<4) swizzle. Staged via pre-swizzled global source.
__global__ __launch_bounds__(512, 2) void gemm8p(
    const ushort* __restrict__ Xb, const ushort* __restrict__ Wb,
    const float* __restrict__ scale, const float* __restrict__ bias,
    float* __restrict__ out) {
  __shared__ __align__(16) char L[131072];

  // T1: 512 blocks, 8 XCDs x 64; within XCD: nt fastest (B-panel L2 reuse)
  int bid = blockIdx.x;
  int g = (bid & 7) * 64 + (bid >> 3);
  int mt = g >> 2, nt = g & 3;
  int rowBase = mt * 256, colBase = nt * 256;

  int tid = threadIdx.x, lane = tid & 63, w = tid >> 6;
  int wm = w >> 2, wn = w & 3;          // wave grid 2M x 4N; 128x64 out/wave

  // frag read offsets: row&7 == lane&7 for all frags -> uniform XOR
  int baseA = (wm * 128 + (lane & 15)) * 128;
  int baseB = 65536 + (wn * 64 + (lane & 15)) * 128;
  int c0 = ((lane >> 4) * 16) ^ ((lane & 7) << 4);   // kslice 0
  int c1 = c0 ^ 64;                                   // kslice 1
  // stage source pre-swizzle: row&7 == lane>>3 (row0 always %8==0)
  int srl = lane >> 3;
  int scb = ((lane & 7) ^ srl) * 8;                   // ushort offset
  int bu0 = (w & 3) * 8 + (w >> 2) * 64;              // B-unit0 wave row0
  const ushort* gA = Xb + ((size_t)rowBase + srl) * IN_F + scb;
  const ushort* gB = Wb + ((size_t)colBase + srl) * IN_F + scb;

#define STA(bufOff, kt, row0) \
  gload_lds16(gA + (size_t)(row0) * IN_F + (kt) * 64, L + (bufOff) + (row0) * 128)
#define STB(bufOff, kt, row0) \
  gload_lds16(gB + (size_t)(row0) * IN_F + (kt) * 64, \
              L + 65536 + (bufOff) + (row0) * 128)

  f32x4 acc[8][4];
#pragma unroll
  for (int m = 0; m < 8; ++m)
#pragma unroll
    for (int n = 0; n < 4; ++n) acc[m][n] = (f32x4){0.f, 0.f, 0.f, 0.f};

  // ---- prologue: stage tile0 -> buf0 (8 issues/wave), tile1 -> buf1 (8) ----
  STA(0, 0, w * 8);        STA(0, 0, 128 + w * 8);
  STA(0, 0, 64 + w * 8);   STA(0, 0, 192 + w * 8);
  STB(0, 0, bu0);          STB(0, 0, bu0 + 128);
  STB(0, 0, bu0 + 32);     STB(0, 0, bu0 + 160);
  STA(32768, 1, w * 8);      STA(32768, 1, 128 + w * 8);
  STA(32768, 1, 64 + w * 8); STA(32768, 1, 192 + w * 8);
  STB(32768, 1, bu0);        STB(32768, 1, bu0 + 128);
  STB(32768, 1, bu0 + 32);   STB(32768, 1, bu0 + 160);
  asm volatile("s_waitcnt vmcnt(8)");   // tile0's 8 loads complete
  BAR();

  short8 aLo[4][2], aHi[4][2], bb[2][2];

  for (int it = 0; it < 8; ++it) {
    int kt2 = (2 * it + 2) & 15;        // wraps harmlessly on last iter
    int kt3 = (2 * it + 3) & 15;

    // ======== X half: tile 2it in buf0 ========
    // p1 (q0 = mlo,nlo): 12 ds_reads; no stage
    rd4(aLo, L + baseA, c0, c1);
    rd2(bb, L + baseB, c0, c1);
    MFMA_SEC((mmq<0, 0>(acc, aLo, bb)));
    // p2 (q1 = mhi,nlo): 8 ds_reads; stage A-X' u0
    rd4(aHi, L + baseA + 4 * 2048, c0, c1);
    STA(0, kt2, w * 8); STA(0, kt2, 128 + w * 8);
    MFMA_SEC((mmq<4, 0>(acc, aHi, bb)));
    // p3 (q2 = mhi,nhi): 4 ds_reads; stage B-X' u0
    rd2(bb, L + baseB + 2 * 2048, c0, c1);
    STB(0, kt2, bu0); STB(0, kt2, bu0 + 128);
    MFMA_SEC((mmq<4, 2>(acc, aHi, bb)));
    // p4 (q3 = mlo,nhi): 0 reads; stage A-X' u1; vmcnt(6)
    STA(0, kt2, 64 + w * 8); STA(0, kt2, 192 + w * 8);
    asm volatile("s_waitcnt vmcnt(6)");
    MFMA_SEC((mmq<0, 2>(acc, aLo, bb)));

    // ======== Y half: tile 2it+1 in buf1 ========
    // p5: 12 ds_reads (buf1); stage B-X' u1
    rd4(aLo, L + 32768 + baseA, c0, c1);
    rd2(bb, L + 32768 + baseB, c0, c1);
    STB(0, kt2, bu0 + 32); STB(0, kt2, bu0 + 160);
    MFMA_SEC((mmq<0, 0>(acc, aLo, bb)));
    // p6: 8 ds_reads; stage A-Y' u0
    rd4(aHi, L + 32768 + baseA + 4 * 2048, c0, c1);
    STA(32768, kt3, w * 8); STA(32768, kt3, 128 + w * 8);
    MFMA_SEC((mmq<4, 0>(acc, aHi, bb)));
    // p7: 4 ds_reads; stage B-Y' u0
    rd2(bb, L + 32768 + baseB + 2 * 2048, c0, c1);
    STB(32768, kt3, bu0); STB(32768, kt3, bu0 + 128);
    MFMA_SEC((mmq<4, 2>(acc, aHi, bb)));
    // p8: 0 reads; stage A-Y' u1 + B-Y' u1 (4 issues); vmcnt(6)
    STA(32768, kt3, 64 + w * 8); STA(32768, kt3, 192 + w * 8);
    STB(32768, kt3, bu0 + 32);   STB(32768, kt3, bu0 + 160);
    asm volatile("s_waitcnt vmcnt(6)");
    MFMA_SEC((mmq<0, 2>(acc, aLo, bb)));
  }

  asm volatile("s_waitcnt vmcnt(0)");   // drain stale prefetches

  // epilogue: C/D layout col=lane&15, row=(lane>>4)*4+j (m89-verified)
#pragma unroll
  for (int n = 0; n < 4; ++n) {
    int col = colBase + wn * 64 + n * 16 + (lane & 15);
    float sc = scale[col];
    float bs = bias[col];
#pragma unroll
    for (int m = 0; m < 8; ++m) {
      int r0 = rowBase + wm * 128 + m * 16 + ((lane >> 4) << 2);
#pragma unroll
      for (int j = 0; j < 4; ++j)
        out[(size_t)(r0 + j) * OUT_F + col] = acc[m][n][j] * sc + bs;
    }
  }
#undef STA
#undef STB
}

// ---- Fallback GEMM (R1 structure, reg-staged f32->bf16) ----
__global__ void gemm_kernel(const float* __restrict__ X,
                            const ushort* __restrict__ Wb,
                            const float* __restrict__ scale,
                            const float* __restrict__ bias,
                            float* __restrict__ out) {
  __shared__ __align__(16) ushort lA[128 * 32];
  __shared__ __align__(16) ushort lB[128 * 32];
  int bid = blockIdx.x;
  int g = (bid & 7) * 256 + (bid >> 3);
  int mt = g >> 3, nt = g & 7;
  int rowBase = mt * 128, colBase = nt * 128;
  int t = threadIdx.x, lane = t & 63, wave = t >> 6;
  int wr = wave >> 1, wc = wave & 1;
  f32x4 acc[4][4];
#pragma unroll
  for (int m = 0; m < 4; ++m)
#pragma unroll
    for (int n = 0; n < 4; ++n) acc[m][n] = (f32x4){0.f, 0.f, 0.f, 0.f};
  for (int kk = 0; kk < IN_F / 32; ++kk) {
    int k0 = kk * 32;
    __syncthreads();
#pragma unroll
    for (int i = 0; i < 2; ++i) {
      int idx = t + 256 * i;
      int r = idx >> 2, c16 = idx & 3;
      const float4* gp =
          (const float4*)(X + (size_t)(rowBase + r) * IN_F + k0 + c16 * 8);
      float4 v0 = gp[0];
      float4 v1 = gp[1];
      short8 u;
      u[0] = (short)f2bf(v0.x); u[1] = (short)f2bf(v0.y);
      u[2] = (short)f2bf(v0.z); u[3] = (short)f2bf(v0.w);
      u[4] = (short)f2bf(v1.x); u[5] = (short)f2bf(v1.y);
      u[6] = (short)f2bf(v1.z); u[7] = (short)f2bf(v1.w);
      int off = (r * 32 + c16 * 8) ^ ((r & 7) << 3);
      *(short8*)(&lA[off]) = u;
      const short8* gp2 =
          (const short8*)(Wb + (size_t)(colBase + r) * IN_F + k0 + c16 * 8);
      *(short8*)(&lB[off]) = *gp2;
    }
    __syncthreads();
    short8 af[4], bfr[4];
#pragma unroll
    for (int m = 0; m < 4; ++m) {
      int r = wr * 64 + m * 16 + (lane & 15);
      int off = (r * 32 + (lane >> 4) * 8) ^ ((r & 7) << 3);
      af[m] = *(const short8*)(&lA[off]);
    }
#pragma unroll
    for (int n = 0; n < 4; ++n) {
      int r = wc * 64 + n * 16 + (lane & 15);
      int off = (r * 32 + (lane >> 4) * 8) ^ ((r & 7) << 3);
      bfr[n] = *(const short8*)(&lB[off]);
    }
#pragma unroll
    for (int m = 0; m < 4; ++m)
#pragma unroll
      for (int n = 0; n < 4; ++n)
        acc[m][n] = __builtin_amdgcn_mfma_f32_16x16x32_bf16(
            af[m], bfr[n], acc[m][n], 0, 0, 0);
  }
#pragma unroll
  for (int n = 0; n < 4; ++n) {
    int col = colBase + wc * 64 + n * 16 + (lane & 15);
    float sc = scale[col];
    float bs = bias[col];
#pragma unroll
    for (int m = 0; m < 4; ++m) {
      int r0 = rowBase + wr * 64 + m * 16 + ((lane >> 4) << 2);
#pragma unroll
      for (int j = 0; j < 4; ++j)
        out[(size_t)(r0 + j) * OUT_F + col] = acc[m][n][j] * sc + bs;
    }
  }
}

extern "C" void kernel_launch(void* const* d_in, const int* in_sizes, int n_in,
                              void* d_out, int out_size, void* d_ws,
                              size_t ws_size, hipStream_t stream) {
  const float* x = (const float*)d_in[0];
  const float* W = (const float*)d_in[1];
  const float* b = (const float*)d_in[2];
  float* out = (float*)d_out;

  float* scale = (float*)d_ws;                               // 4 KB
  ushort* Wb = (ushort*)((char*)d_ws + 4096);                // 2 MB
  ushort* xb = (ushort*)((char*)d_ws + 4096 + 2097152);      // 64 MB
  const size_t need = 4096 + 2097152 + (size_t)BATCH * IN_F * 2;

  bin_kernel<<<OUT_F / 4, 256, 0, stream>>>(W, Wb, scale);

  if (ws_size >= need) {
    cvt_kernel<<<(BATCH * IN_F / 4) / 256, 256, 0, stream>>>(x, xb);
    gemm8p<<<(BATCH / 256) * (OUT_F / 256), 512, 0, stream>>>(xb, Wb, scale,
                                                              b, out);
  } else {
    gemm_kernel<<<(BATCH / 128) * (OUT_F / 128), 256, 0, stream>>>(
        x, Wb, scale, b, out);
  }
}